// Round 5
// baseline (191.331 us; speedup 1.0000x reference)
//
#include <hip/hip_runtime.h>
#include <hip/hip_bf16.h>

#define BB 4096
#define TT 200
#define LL 8
#define VV 64
#define CC 16
#define NBERN 32
#define CLIP 20.0f
#define TC 20                       // t per chunk
#define NCH (TT / TC)               // 10 chunks per b
#define TOTCH (BB * NCH)            // 40960 chunks
#define LBLK 2048                   // link blocks
#define LWAVES (LBLK * 4)           // 8192 waves
#define CPW (TOTCH / LWAVES)        // 5 chunks per wave
#define CF4 (TC * CC / 4)           // 80 float4 of x per chunk
#define ZF4 (TC * LL / 4)           // 40 float4 of z per chunk
#define BUF4 (CF4 + ZF4)            // 120 float4 per chunk buffer

// ---------------- Phase A: z recurrence, 8 lanes per b ----------------
__global__ __launch_bounds__(256) void var1_fast(
    const float* __restrict__ eps,        // (B,T,L)
    const float* __restrict__ A,          // (L,L)
    const float* __restrict__ logvar_z1,  // (L)
    const float* __restrict__ beta0,      // (L)
    const float* __restrict__ beta1,      // (L)
    float* __restrict__ zout)             // (B,T,L) in ws
{
    const int tid  = blockIdx.x * 256 + threadIdx.x;
    const int b    = tid >> 3;
    const int j    = tid & 7;
    const int lane = threadIdx.x & 63;
    const int gbase = lane & 56;

    float Acol[LL];
#pragma unroll
    for (int l = 0; l < LL; ++l) Acol[l] = A[l * LL + j];
    const float bb0 = beta0[j];
    const float bb1 = beta1[j];
    const float s1  = __expf(0.5f * logvar_z1[j]);

    const float* ep = eps + (size_t)b * TT * LL + j;
    float* zb = zout + (size_t)b * TT * LL + j;

    float zj = ep[0] * s1;
    zb[0] = zj;

    float ebuf[4];
#pragma unroll
    for (int k = 0; k < 4; ++k) ebuf[k] = ep[(size_t)(1 + k) * LL];

#pragma unroll 4
    for (int t = 1; t < TT; ++t) {
        const int slot = (t - 1) & 3;
        const float cur = ebuf[slot];
        const int tn = t + 4;
        if (tn < TT) ebuf[slot] = ep[(size_t)tn * LL];

        float a = fmaf(bb1, (float)t, bb0) + cur;
#pragma unroll
        for (int l = 0; l < LL; ++l) {
            const float zl = __shfl(zj, gbase + l);
            a = fmaf(zl, Acol[l], a);
        }
        zj = a;
        zb[(size_t)t * LL] = zj;
    }
}

// ---------------- Phase B: link map, grid-stride + wave-private double-buffer ----
__global__ __launch_bounds__(256, 8) void link_v3(
    const float* __restrict__ z,          // (B,T,L) from ws
    const float* __restrict__ u,          // (B,1,V)
    const float* __restrict__ x,          // (B,T,C)
    const float* __restrict__ intercepts, // (V)
    const float* __restrict__ wz,         // (L,V)
    const float* __restrict__ wx,         // (C,V)
    const float* __restrict__ logvar_u,   // (V)
    float* __restrict__ linpar_out,       // (B,T,V)
    float* __restrict__ condmean_out)     // (B,T,V)
{
    const int w    = threadIdx.x >> 6;
    const int lane = threadIdx.x & 63;
    const int v    = lane;
    const int gw   = blockIdx.x * 4 + w;

    __shared__ __align__(16) float4 lds[4][2][BUF4];   // 15.4 KB/block

    float wxv[CC];
#pragma unroll
    for (int c = 0; c < CC; ++c) wxv[c] = wx[c * VV + v];
    float wzv[LL];
#pragma unroll
    for (int l = 0; l < LL; ++l) wzv[l] = wz[l * VV + v];
    const float ivp = intercepts[v];
    const float su  = __expf(0.5f * logvar_u[v]);

    const int ch0  = gw * CPW;            // my contiguous chunk range
    const int chEnd = ch0 + CPW;

    // ---- stage helpers (wave-private, no barriers) ----
    auto stage_load = [&](int ch, float4& r0, float4& r1) {
        const int b  = ch / NCH;
        const int t0 = (ch - b * NCH) * TC;
        const float4* gx4 = (const float4*)(x + ((size_t)b * TT + t0) * CC);
        const float4* gz4 = (const float4*)(z + ((size_t)b * TT + t0) * LL);
        r0 = gx4[lane];
        const int i1 = 64 + lane;
        if (i1 < CF4)       r1 = gx4[i1];
        else if (i1 < BUF4) r1 = gz4[i1 - CF4];
    };
    auto stage_write = [&](float4* buf, const float4& r0, const float4& r1) {
        buf[lane] = r0;
        if (64 + lane < BUF4) buf[64 + lane] = r1;
    };

    // prologue: chunk ch0 -> buf0
    float4 r0, r1;
    stage_load(ch0, r0, r1);
    stage_write(lds[w][0], r0, r1);

    int cur = 0;
    for (int ch = ch0; ch < chEnd; ++ch) {
        // issue next chunk's global loads now (hidden under compute)
        float4 n0, n1;
        const int chn = (ch + 1 < TOTCH) ? (ch + 1) : (TOTCH - 1);
        stage_load(chn, n0, n1);

        const int b  = ch / NCH;
        const int t0 = (ch - b * NCH) * TC;
        const float base = ivp + u[(size_t)b * VV + v] * su;

        const float4* xs4 = lds[w][cur];
        const float4* zs4 = lds[w][cur] + CF4;
        float* lp = linpar_out   + ((size_t)b * TT + t0) * VV + v;
        float* cm = condmean_out + ((size_t)b * TT + t0) * VV + v;

#pragma unroll 2
        for (int tt = 0; tt < TC; ++tt) {
            const float4 x0 = xs4[tt * 4 + 0], x1 = xs4[tt * 4 + 1];
            const float4 x2 = xs4[tt * 4 + 2], x3 = xs4[tt * 4 + 3];
            const float4 z0 = zs4[tt * 2 + 0], z1 = zs4[tt * 2 + 1];

            float a0 = base, a1 = 0.f, a2 = 0.f, a3 = 0.f;
            a0 = fmaf(x0.x, wxv[0],  a0); a0 = fmaf(x0.y, wxv[1],  a0);
            a0 = fmaf(x0.z, wxv[2],  a0); a0 = fmaf(x0.w, wxv[3],  a0);
            a1 = fmaf(x1.x, wxv[4],  a1); a1 = fmaf(x1.y, wxv[5],  a1);
            a1 = fmaf(x1.z, wxv[6],  a1); a1 = fmaf(x1.w, wxv[7],  a1);
            a2 = fmaf(x2.x, wxv[8],  a2); a2 = fmaf(x2.y, wxv[9],  a2);
            a2 = fmaf(x2.z, wxv[10], a2); a2 = fmaf(x2.w, wxv[11], a2);
            a3 = fmaf(x3.x, wxv[12], a3); a3 = fmaf(x3.y, wxv[13], a3);
            a3 = fmaf(x3.z, wxv[14], a3); a3 = fmaf(x3.w, wxv[15], a3);
            a0 = fmaf(z0.x, wzv[0],  a0); a0 = fmaf(z0.y, wzv[1],  a0);
            a1 = fmaf(z0.z, wzv[2],  a1); a1 = fmaf(z0.w, wzv[3],  a1);
            a2 = fmaf(z1.x, wzv[4],  a2); a2 = fmaf(z1.y, wzv[5],  a2);
            a3 = fmaf(z1.z, wzv[6],  a3); a3 = fmaf(z1.w, wzv[7],  a3);

            float acc = (a0 + a1) + (a2 + a3);
            acc = fminf(fmaxf(acc, -CLIP), CLIP);
            const float cmv = (v < NBERN) ? (1.0f / (1.0f + __expf(-acc)))
                                          : __expf(acc);
            lp[(size_t)tt * VV] = acc;
            cm[(size_t)tt * VV] = cmv;
        }

        // deposit prefetched chunk into the other buffer
        stage_write(lds[w][cur ^ 1], n0, n1);
        cur ^= 1;
    }
}

// ---------------- fallback: fused kernel (if ws too small) ----------------
__global__ __launch_bounds__(256) void vargllvm_fused(
    const float* __restrict__ eps, const float* __restrict__ u,
    const float* __restrict__ x, const float* __restrict__ A,
    const float* __restrict__ logvar_z1, const float* __restrict__ beta0,
    const float* __restrict__ beta1, const float* __restrict__ intercepts,
    const float* __restrict__ wz, const float* __restrict__ wx,
    const float* __restrict__ logvar_u,
    float* __restrict__ linpar_out, float* __restrict__ condmean_out)
{
    const int wave = threadIdx.x >> 6;
    const int lane = threadIdx.x & 63;
    const int b    = blockIdx.x * 4 + wave;
    const int v    = lane;

    float wxv[CC];
#pragma unroll
    for (int c = 0; c < CC; ++c) wxv[c] = wx[c * VV + v];
    float wzv[LL];
#pragma unroll
    for (int l = 0; l < LL; ++l) wzv[l] = wz[l * VV + v];
    const float base = intercepts[v] + u[(size_t)b * VV + v] * __expf(0.5f * logvar_u[v]);

    float Ar[LL][LL];
#pragma unroll
    for (int l = 0; l < LL; ++l)
#pragma unroll
        for (int j = 0; j < LL; ++j) Ar[l][j] = A[l * LL + j];
    float b0[LL], b1[LL];
#pragma unroll
    for (int j = 0; j < LL; ++j) { b0[j] = beta0[j]; b1[j] = beta1[j]; }

    const float* epsb = eps + (size_t)b * TT * LL;
    const float* xb   = x   + (size_t)b * TT * CC;
    float* lp = linpar_out   + (size_t)b * TT * VV + v;
    float* cm = condmean_out + (size_t)b * TT * VV + v;

    float zv[LL];
#pragma unroll
    for (int j = 0; j < LL; ++j) zv[j] = epsb[j] * __expf(0.5f * logvar_z1[j]);

    for (int t = 0; t < TT; ++t) {
        if (t > 0) {
            float zn[LL];
            const float tf = (float)t;
#pragma unroll
            for (int j = 0; j < LL; ++j) {
                float a = fmaf(b1[j], tf, b0[j]) + epsb[t * LL + j];
#pragma unroll
                for (int l = 0; l < LL; ++l) a = fmaf(zv[l], Ar[l][j], a);
                zn[j] = a;
            }
#pragma unroll
            for (int j = 0; j < LL; ++j) zv[j] = zn[j];
        }
        float acc = base;
#pragma unroll
        for (int c = 0; c < CC; ++c) acc = fmaf(xb[t * CC + c], wxv[c], acc);
#pragma unroll
        for (int l = 0; l < LL; ++l) acc = fmaf(zv[l], wzv[l], acc);
        acc = fminf(fmaxf(acc, -CLIP), CLIP);
        float cmv = (v < NBERN) ? (1.0f / (1.0f + __expf(-acc))) : __expf(acc);
        lp[(size_t)t * VV] = acc;
        cm[(size_t)t * VV] = cmv;
    }
}

extern "C" void kernel_launch(void* const* d_in, const int* in_sizes, int n_in,
                              void* d_out, int out_size, void* d_ws, size_t ws_size,
                              hipStream_t stream) {
    const float* eps        = (const float*)d_in[0];
    const float* u          = (const float*)d_in[1];
    const float* x          = (const float*)d_in[2];
    const float* A          = (const float*)d_in[3];
    const float* logvar_z1  = (const float*)d_in[4];
    const float* beta0      = (const float*)d_in[5];
    const float* beta1      = (const float*)d_in[6];
    const float* intercepts = (const float*)d_in[7];
    const float* wz         = (const float*)d_in[8];
    const float* wx         = (const float*)d_in[9];
    const float* logvar_u   = (const float*)d_in[10];

    float* linpar   = (float*)d_out;
    float* condmean = (float*)d_out + (size_t)BB * TT * VV;

    const size_t z_bytes = (size_t)BB * TT * LL * sizeof(float);
    if (ws_size >= z_bytes) {
        float* zws = (float*)d_ws;
        hipLaunchKernelGGL(var1_fast, dim3(BB * LL / 256), dim3(256), 0, stream,
                           eps, A, logvar_z1, beta0, beta1, zws);
        hipLaunchKernelGGL(link_v3, dim3(LBLK), dim3(256), 0, stream,
                           zws, u, x, intercepts, wz, wx, logvar_u, linpar, condmean);
    } else {
        hipLaunchKernelGGL(vargllvm_fused, dim3(BB / 4), dim3(256), 0, stream,
                           eps, u, x, A, logvar_z1, beta0, beta1,
                           intercepts, wz, wx, logvar_u, linpar, condmean);
    }
}

// Round 6
// 149.106 us; speedup vs baseline: 1.2832x; 1.2832x over previous
//
#include <hip/hip_runtime.h>
#include <hip/hip_bf16.h>

#define BB 4096
#define TT 200
#define LL 8
#define VV 64
#define CC 16
#define KK (CC + LL)                // 24
#define NBERN 32
#define CLIP 20.0f

#define ROWS (BB * TT)              // 819200 flattened (b,t) rows
#define RPC 64                      // rows per chunk (= per wave tile)
#define NCHK (ROWS / RPC)           // 12800 chunks, exact
#define WPB 4                       // waves per block
#define LBLK (NCHK / WPB)           // 3200 blocks

// ---------------- Phase A: z recurrence, 8 lanes per b ----------------
__global__ __launch_bounds__(256) void var1_fast(
    const float* __restrict__ eps,        // (B,T,L)
    const float* __restrict__ A,          // (L,L)
    const float* __restrict__ logvar_z1,  // (L)
    const float* __restrict__ beta0,      // (L)
    const float* __restrict__ beta1,      // (L)
    float* __restrict__ zout)             // (B,T,L) in ws
{
    const int tid  = blockIdx.x * 256 + threadIdx.x;
    const int b    = tid >> 3;
    const int j    = tid & 7;
    const int lane = threadIdx.x & 63;
    const int gbase = lane & 56;

    float Acol[LL];
#pragma unroll
    for (int l = 0; l < LL; ++l) Acol[l] = A[l * LL + j];
    const float bb0 = beta0[j];
    const float bb1 = beta1[j];
    const float s1  = __expf(0.5f * logvar_z1[j]);

    const float* ep = eps + (size_t)b * TT * LL + j;
    float* zb = zout + (size_t)b * TT * LL + j;

    float zj = ep[0] * s1;
    zb[0] = zj;

    float ebuf[4];
#pragma unroll
    for (int k = 0; k < 4; ++k) ebuf[k] = ep[(size_t)(1 + k) * LL];

#pragma unroll 4
    for (int t = 1; t < TT; ++t) {
        const int slot = (t - 1) & 3;
        const float cur = ebuf[slot];
        const int tn = t + 4;
        if (tn < TT) ebuf[slot] = ep[(size_t)tn * LL];

        float a = fmaf(bb1, (float)t, bb0) + cur;
#pragma unroll
        for (int l = 0; l < LL; ++l) {
            const float zl = __shfl(zj, gbase + l);
            a = fmaf(zl, Acol[l], a);
        }
        zj = a;
        zb[(size_t)t * LL] = zj;
    }
}

// ---------------- Phase B: register-tiled link map ----------------
// Wave = 64 rows x 64 v tile; lane owns 8 rows x 8 v.
// XZ[k][row] k-major in LDS (transposed at staging); W[k][v] staged per block.
__global__ __launch_bounds__(256) void link_tiled(
    const float* __restrict__ z,          // (B,T,L) from ws
    const float* __restrict__ u,          // (B,1,V)
    const float* __restrict__ x,          // (B,T,C)
    const float* __restrict__ intercepts, // (V)
    const float* __restrict__ wz,         // (L,V)
    const float* __restrict__ wx,         // (C,V)
    const float* __restrict__ logvar_u,   // (V)
    float* __restrict__ lp_out,           // (B,T,V)
    float* __restrict__ cm_out)           // (B,T,V)
{
    const int w    = threadIdx.x >> 6;
    const int lane = threadIdx.x & 63;
    const int tr   = lane >> 3;           // row group 0..7
    const int vc   = lane & 7;            // v octet 0..7

    __shared__ __align__(16) float W[KK][RPC];        // 6 KB
    __shared__ __align__(16) float XZ[WPB][KK][RPC];  // 24 KB

    // stage weights block-wide: rows 0..15 = wx, 16..23 = wz (both (K,V) row-major)
    for (int i = threadIdx.x; i < KK * VV; i += 256)
        ((float*)W)[i] = (i < CC * VV) ? wx[i] : wz[i - CC * VV];
    __syncthreads();

    const int    gw = blockIdx.x * WPB + w;
    const size_t r0 = (size_t)gw * RPC;   // first flattened row of this wave's tile

    // ---- stage XZ transposed (wave-private, no barrier) ----
    {
        const float* xr = x + (r0 + lane) * CC;
        const float4 a0 = *(const float4*)(xr);
        const float4 a1 = *(const float4*)(xr + 4);
        const float4 a2 = *(const float4*)(xr + 8);
        const float4 a3 = *(const float4*)(xr + 12);
        const float* zr = z + (r0 + lane) * LL;
        const float4 b0 = *(const float4*)(zr);
        const float4 b1 = *(const float4*)(zr + 4);

        XZ[w][ 0][lane] = a0.x; XZ[w][ 1][lane] = a0.y;
        XZ[w][ 2][lane] = a0.z; XZ[w][ 3][lane] = a0.w;
        XZ[w][ 4][lane] = a1.x; XZ[w][ 5][lane] = a1.y;
        XZ[w][ 6][lane] = a1.z; XZ[w][ 7][lane] = a1.w;
        XZ[w][ 8][lane] = a2.x; XZ[w][ 9][lane] = a2.y;
        XZ[w][10][lane] = a2.z; XZ[w][11][lane] = a2.w;
        XZ[w][12][lane] = a3.x; XZ[w][13][lane] = a3.y;
        XZ[w][14][lane] = a3.z; XZ[w][15][lane] = a3.w;
        XZ[w][16][lane] = b0.x; XZ[w][17][lane] = b0.y;
        XZ[w][18][lane] = b0.z; XZ[w][19][lane] = b0.w;
        XZ[w][20][lane] = b1.x; XZ[w][21][lane] = b1.y;
        XZ[w][22][lane] = b1.z; XZ[w][23][lane] = b1.w;
    }

    // ---- k-loop: acc[i][j] += XZ[k][tr*8+i] * W[k][vc*8+j] ----
    float acc[8][8];
#pragma unroll
    for (int i = 0; i < 8; ++i)
#pragma unroll
        for (int j = 0; j < 8; ++j) acc[i][j] = 0.f;

#pragma unroll 4
    for (int k = 0; k < KK; ++k) {
        const float4 xa = *(const float4*)&XZ[w][k][tr * 8];
        const float4 xb = *(const float4*)&XZ[w][k][tr * 8 + 4];
        const float4 wa = *(const float4*)&W[k][vc * 8];
        const float4 wb = *(const float4*)&W[k][vc * 8 + 4];
        const float xv[8] = {xa.x, xa.y, xa.z, xa.w, xb.x, xb.y, xb.z, xb.w};
        const float wv[8] = {wa.x, wa.y, wa.z, wa.w, wb.x, wb.y, wb.z, wb.w};
#pragma unroll
        for (int i = 0; i < 8; ++i)
#pragma unroll
            for (int j = 0; j < 8; ++j)
                acc[i][j] = fmaf(xv[i], wv[j], acc[i][j]);
    }

    // ---- epilogue: base add, clip, links, coalesced stores ----
    const int vbase = vc * 8;
    const float4 ic0 = *(const float4*)(intercepts + vbase);
    const float4 ic1 = *(const float4*)(intercepts + vbase + 4);
    const float4 lv0 = *(const float4*)(logvar_u + vbase);
    const float4 lv1 = *(const float4*)(logvar_u + vbase + 4);
    const float ic[8] = {ic0.x, ic0.y, ic0.z, ic0.w, ic1.x, ic1.y, ic1.z, ic1.w};
    const float su[8] = {__expf(0.5f * lv0.x), __expf(0.5f * lv0.y),
                         __expf(0.5f * lv0.z), __expf(0.5f * lv0.w),
                         __expf(0.5f * lv1.x), __expf(0.5f * lv1.y),
                         __expf(0.5f * lv1.z), __expf(0.5f * lv1.w)};
    const bool sig = (vc < 4);            // lane-uniform: all 8 v on same side of 32

#pragma unroll
    for (int i = 0; i < 8; ++i) {
        const size_t   r  = r0 + (size_t)tr * 8 + i;
        const unsigned b  = (unsigned)r / 200u;       // compiler magic-div
        const float4 u0 = *(const float4*)(u + (size_t)b * VV + vbase);
        const float4 u1 = *(const float4*)(u + (size_t)b * VV + vbase + 4);
        const float uu[8] = {u0.x, u0.y, u0.z, u0.w, u1.x, u1.y, u1.z, u1.w};

        float lpv[8], cmv[8];
#pragma unroll
        for (int j = 0; j < 8; ++j) {
            float a = acc[i][j] + fmaf(uu[j], su[j], ic[j]);
            a = fminf(fmaxf(a, -CLIP), CLIP);
            const float arg = sig ? -a : a;
            const float E   = __expf(arg);
            const float rs  = __builtin_amdgcn_rcpf(1.0f + E);  // sigmoid branch
            cmv[j] = sig ? rs : E;
            lpv[j] = a;
        }
        float4* lpp = (float4*)(lp_out + r * VV + vbase);
        lpp[0] = make_float4(lpv[0], lpv[1], lpv[2], lpv[3]);
        lpp[1] = make_float4(lpv[4], lpv[5], lpv[6], lpv[7]);
        float4* cmp = (float4*)(cm_out + r * VV + vbase);
        cmp[0] = make_float4(cmv[0], cmv[1], cmv[2], cmv[3]);
        cmp[1] = make_float4(cmv[4], cmv[5], cmv[6], cmv[7]);
    }
}

// ---------------- fallback: fused kernel (if ws too small) ----------------
__global__ __launch_bounds__(256) void vargllvm_fused(
    const float* __restrict__ eps, const float* __restrict__ u,
    const float* __restrict__ x, const float* __restrict__ A,
    const float* __restrict__ logvar_z1, const float* __restrict__ beta0,
    const float* __restrict__ beta1, const float* __restrict__ intercepts,
    const float* __restrict__ wz, const float* __restrict__ wx,
    const float* __restrict__ logvar_u,
    float* __restrict__ linpar_out, float* __restrict__ condmean_out)
{
    const int wave = threadIdx.x >> 6;
    const int lane = threadIdx.x & 63;
    const int b    = blockIdx.x * 4 + wave;
    const int v    = lane;

    float wxv[CC];
#pragma unroll
    for (int c = 0; c < CC; ++c) wxv[c] = wx[c * VV + v];
    float wzv[LL];
#pragma unroll
    for (int l = 0; l < LL; ++l) wzv[l] = wz[l * VV + v];
    const float base = intercepts[v] + u[(size_t)b * VV + v] * __expf(0.5f * logvar_u[v]);

    float Ar[LL][LL];
#pragma unroll
    for (int l = 0; l < LL; ++l)
#pragma unroll
        for (int j = 0; j < LL; ++j) Ar[l][j] = A[l * LL + j];
    float b0[LL], b1[LL];
#pragma unroll
    for (int j = 0; j < LL; ++j) { b0[j] = beta0[j]; b1[j] = beta1[j]; }

    const float* epsb = eps + (size_t)b * TT * LL;
    const float* xb   = x   + (size_t)b * TT * CC;
    float* lp = linpar_out   + (size_t)b * TT * VV + v;
    float* cm = condmean_out + (size_t)b * TT * VV + v;

    float zv[LL];
#pragma unroll
    for (int j = 0; j < LL; ++j) zv[j] = epsb[j] * __expf(0.5f * logvar_z1[j]);

    for (int t = 0; t < TT; ++t) {
        if (t > 0) {
            float zn[LL];
            const float tf = (float)t;
#pragma unroll
            for (int j = 0; j < LL; ++j) {
                float a = fmaf(b1[j], tf, b0[j]) + epsb[t * LL + j];
#pragma unroll
                for (int l = 0; l < LL; ++l) a = fmaf(zv[l], Ar[l][j], a);
                zn[j] = a;
            }
#pragma unroll
            for (int j = 0; j < LL; ++j) zv[j] = zn[j];
        }
        float acc = base;
#pragma unroll
        for (int c = 0; c < CC; ++c) acc = fmaf(xb[t * CC + c], wxv[c], acc);
#pragma unroll
        for (int l = 0; l < LL; ++l) acc = fmaf(zv[l], wzv[l], acc);
        acc = fminf(fmaxf(acc, -CLIP), CLIP);
        float cmv = (v < NBERN) ? (1.0f / (1.0f + __expf(-acc))) : __expf(acc);
        lp[(size_t)t * VV] = acc;
        cm[(size_t)t * VV] = cmv;
    }
}

extern "C" void kernel_launch(void* const* d_in, const int* in_sizes, int n_in,
                              void* d_out, int out_size, void* d_ws, size_t ws_size,
                              hipStream_t stream) {
    const float* eps        = (const float*)d_in[0];
    const float* u          = (const float*)d_in[1];
    const float* x          = (const float*)d_in[2];
    const float* A          = (const float*)d_in[3];
    const float* logvar_z1  = (const float*)d_in[4];
    const float* beta0      = (const float*)d_in[5];
    const float* beta1      = (const float*)d_in[6];
    const float* intercepts = (const float*)d_in[7];
    const float* wz         = (const float*)d_in[8];
    const float* wx         = (const float*)d_in[9];
    const float* logvar_u   = (const float*)d_in[10];

    float* linpar   = (float*)d_out;
    float* condmean = (float*)d_out + (size_t)BB * TT * VV;

    const size_t z_bytes = (size_t)BB * TT * LL * sizeof(float);
    if (ws_size >= z_bytes) {
        float* zws = (float*)d_ws;
        hipLaunchKernelGGL(var1_fast, dim3(BB * LL / 256), dim3(256), 0, stream,
                           eps, A, logvar_z1, beta0, beta1, zws);
        hipLaunchKernelGGL(link_tiled, dim3(LBLK), dim3(256), 0, stream,
                           zws, u, x, intercepts, wz, wx, logvar_u, linpar, condmean);
    } else {
        hipLaunchKernelGGL(vargllvm_fused, dim3(BB / 4), dim3(256), 0, stream,
                           eps, u, x, A, logvar_z1, beta0, beta1,
                           intercepts, wz, wx, logvar_u, linpar, condmean);
    }
}

// Round 7
// 106.860 us; speedup vs baseline: 1.7905x; 1.3953x over previous
//
#include <hip/hip_runtime.h>
#include <hip/hip_bf16.h>

#define BB 4096
#define TT 200
#define LL 8
#define VV 64
#define CC 16
#define NBERN 32
#define CLIP 20.0f
#define TC 25                       // t per chunk
#define NCH (TT / TC)               // 8 chunks per b
#define TOTW (BB * NCH)             // 32768 waves
#define WPB 4
#define LBLK (TOTW / WPB)           // 8192 blocks
#define XF4 (TC * CC / 4)           // 100 float4 of x per chunk
#define ZF4 (TC * LL / 4)           // 50 float4 of z per chunk
#define BUF4T (XF4 + ZF4)           // 150 float4 per wave buffer

// ---------------- Phase A: z recurrence, 8 lanes per b ----------------
__global__ __launch_bounds__(256) void var1_fast(
    const float* __restrict__ eps,        // (B,T,L)
    const float* __restrict__ A,          // (L,L)
    const float* __restrict__ logvar_z1,  // (L)
    const float* __restrict__ beta0,      // (L)
    const float* __restrict__ beta1,      // (L)
    float* __restrict__ zout)             // (B,T,L) in ws
{
    const int tid  = blockIdx.x * 256 + threadIdx.x;
    const int b    = tid >> 3;
    const int j    = tid & 7;
    const int lane = threadIdx.x & 63;
    const int gbase = lane & 56;

    float Acol[LL];
#pragma unroll
    for (int l = 0; l < LL; ++l) Acol[l] = A[l * LL + j];
    const float bb0 = beta0[j];
    const float bb1 = beta1[j];
    const float s1  = __expf(0.5f * logvar_z1[j]);

    const float* ep = eps + (size_t)b * TT * LL + j;
    float* zb = zout + (size_t)b * TT * LL + j;

    float zj = ep[0] * s1;
    zb[0] = zj;

    float ebuf[4];
#pragma unroll
    for (int k = 0; k < 4; ++k) ebuf[k] = ep[(size_t)(1 + k) * LL];

#pragma unroll 4
    for (int t = 1; t < TT; ++t) {
        const int slot = (t - 1) & 3;
        const float cur = ebuf[slot];
        const int tn = t + 4;
        if (tn < TT) ebuf[slot] = ep[(size_t)tn * LL];

        float a = fmaf(bb1, (float)t, bb0) + cur;
#pragma unroll
        for (int l = 0; l < LL; ++l) {
            const float zl = __shfl(zj, gbase + l);
            a = fmaf(zl, Acol[l], a);
        }
        zj = a;
        zb[(size_t)t * LL] = zj;
    }
}

// ---------------- Phase B: link map, LDS broadcast + NT stores ----------------
// One wave per (b, 25-t chunk). lane = v. Outputs bypass L2 (non-temporal).
__global__ __launch_bounds__(256) void link_nt(
    const float* __restrict__ z,          // (B,T,L) from ws
    const float* __restrict__ u,          // (B,1,V)
    const float* __restrict__ x,          // (B,T,C)
    const float* __restrict__ intercepts, // (V)
    const float* __restrict__ wz,         // (L,V)
    const float* __restrict__ wx,         // (C,V)
    const float* __restrict__ logvar_u,   // (V)
    float* __restrict__ lp_out,           // (B,T,V)
    float* __restrict__ cm_out)           // (B,T,V)
{
    const int w    = threadIdx.x >> 6;
    const int lane = threadIdx.x & 63;
    const int gw   = blockIdx.x * WPB + w;
    const int b    = gw >> 3;             // NCH = 8
    const int t0   = (gw & 7) * TC;
    const int v    = lane;

    __shared__ __align__(16) float4 buf[WPB][BUF4T];   // 9.6 KB/block

    float wxv[CC];
#pragma unroll
    for (int c = 0; c < CC; ++c) wxv[c] = wx[c * VV + v];
    float wzv[LL];
#pragma unroll
    for (int l = 0; l < LL; ++l) wzv[l] = wz[l * VV + v];
    const float base = intercepts[v] + u[(size_t)b * VV + v] * __expf(0.5f * logvar_u[v]);

    // stage chunk (wave-private; coalesced float4)
    const float4* gx4 = (const float4*)(x + ((size_t)b * TT + t0) * CC);
    const float4* gz4 = (const float4*)(z + ((size_t)b * TT + t0) * LL);
    float4* bw = buf[w];
    {
        const int i0 = lane;
        bw[i0] = (i0 < XF4) ? gx4[i0] : gz4[i0 - XF4];
        const int i1 = lane + 64;
        bw[i1] = (i1 < XF4) ? gx4[i1] : gz4[i1 - XF4];
        const int i2 = lane + 128;
        if (i2 < BUF4T) bw[i2] = gz4[i2 - XF4];
    }

    const float4* xs4 = bw;               // x: 4 float4 per t
    const float4* zs4 = bw + XF4;         // z: 2 float4 per t

    float* lp = lp_out + ((size_t)b * TT + t0) * VV + v;
    float* cm = cm_out + ((size_t)b * TT + t0) * VV + v;

    // explicit current/next register sets: next-t ds_reads issue during compute
    float4 cx0 = xs4[0], cx1 = xs4[1], cx2 = xs4[2], cx3 = xs4[3];
    float4 cz0 = zs4[0], cz1 = zs4[1];

    for (int tt = 0; tt < TC; ++tt) {
        float4 nx0, nx1, nx2, nx3, nz0, nz1;
        if (tt + 1 < TC) {
            nx0 = xs4[(tt + 1) * 4 + 0]; nx1 = xs4[(tt + 1) * 4 + 1];
            nx2 = xs4[(tt + 1) * 4 + 2]; nx3 = xs4[(tt + 1) * 4 + 3];
            nz0 = zs4[(tt + 1) * 2 + 0]; nz1 = zs4[(tt + 1) * 2 + 1];
        }

        float a0 = base, a1 = 0.f, a2 = 0.f, a3 = 0.f;
        a0 = fmaf(cx0.x, wxv[0],  a0); a0 = fmaf(cx0.y, wxv[1],  a0);
        a0 = fmaf(cx0.z, wxv[2],  a0); a0 = fmaf(cx0.w, wxv[3],  a0);
        a1 = fmaf(cx1.x, wxv[4],  a1); a1 = fmaf(cx1.y, wxv[5],  a1);
        a1 = fmaf(cx1.z, wxv[6],  a1); a1 = fmaf(cx1.w, wxv[7],  a1);
        a2 = fmaf(cx2.x, wxv[8],  a2); a2 = fmaf(cx2.y, wxv[9],  a2);
        a2 = fmaf(cx2.z, wxv[10], a2); a2 = fmaf(cx2.w, wxv[11], a2);
        a3 = fmaf(cx3.x, wxv[12], a3); a3 = fmaf(cx3.y, wxv[13], a3);
        a3 = fmaf(cx3.z, wxv[14], a3); a3 = fmaf(cx3.w, wxv[15], a3);
        a0 = fmaf(cz0.x, wzv[0],  a0); a0 = fmaf(cz0.y, wzv[1],  a0);
        a1 = fmaf(cz0.z, wzv[2],  a1); a1 = fmaf(cz0.w, wzv[3],  a1);
        a2 = fmaf(cz1.x, wzv[4],  a2); a2 = fmaf(cz1.y, wzv[5],  a2);
        a3 = fmaf(cz1.z, wzv[6],  a3); a3 = fmaf(cz1.w, wzv[7],  a3);

        float acc = (a0 + a1) + (a2 + a3);
        acc = fminf(fmaxf(acc, -CLIP), CLIP);
        const float cmv = (v < NBERN) ? (1.0f / (1.0f + __expf(-acc)))
                                      : __expf(acc);
        // non-temporal: 419 MB output stream bypasses L2 (never re-read)
        __builtin_nontemporal_store(acc, lp + (size_t)tt * VV);
        __builtin_nontemporal_store(cmv, cm + (size_t)tt * VV);

        cx0 = nx0; cx1 = nx1; cx2 = nx2; cx3 = nx3;
        cz0 = nz0; cz1 = nz1;
    }
}

// ---------------- fallback: fused kernel (if ws too small) ----------------
__global__ __launch_bounds__(256) void vargllvm_fused(
    const float* __restrict__ eps, const float* __restrict__ u,
    const float* __restrict__ x, const float* __restrict__ A,
    const float* __restrict__ logvar_z1, const float* __restrict__ beta0,
    const float* __restrict__ beta1, const float* __restrict__ intercepts,
    const float* __restrict__ wz, const float* __restrict__ wx,
    const float* __restrict__ logvar_u,
    float* __restrict__ linpar_out, float* __restrict__ condmean_out)
{
    const int wave = threadIdx.x >> 6;
    const int lane = threadIdx.x & 63;
    const int b    = blockIdx.x * 4 + wave;
    const int v    = lane;

    float wxv[CC];
#pragma unroll
    for (int c = 0; c < CC; ++c) wxv[c] = wx[c * VV + v];
    float wzv[LL];
#pragma unroll
    for (int l = 0; l < LL; ++l) wzv[l] = wz[l * VV + v];
    const float base = intercepts[v] + u[(size_t)b * VV + v] * __expf(0.5f * logvar_u[v]);

    float Ar[LL][LL];
#pragma unroll
    for (int l = 0; l < LL; ++l)
#pragma unroll
        for (int j = 0; j < LL; ++j) Ar[l][j] = A[l * LL + j];
    float b0[LL], b1[LL];
#pragma unroll
    for (int j = 0; j < LL; ++j) { b0[j] = beta0[j]; b1[j] = beta1[j]; }

    const float* epsb = eps + (size_t)b * TT * LL;
    const float* xb   = x   + (size_t)b * TT * CC;
    float* lp = linpar_out   + (size_t)b * TT * VV + v;
    float* cm = condmean_out + (size_t)b * TT * VV + v;

    float zv[LL];
#pragma unroll
    for (int j = 0; j < LL; ++j) zv[j] = epsb[j] * __expf(0.5f * logvar_z1[j]);

    for (int t = 0; t < TT; ++t) {
        if (t > 0) {
            float zn[LL];
            const float tf = (float)t;
#pragma unroll
            for (int j = 0; j < LL; ++j) {
                float a = fmaf(b1[j], tf, b0[j]) + epsb[t * LL + j];
#pragma unroll
                for (int l = 0; l < LL; ++l) a = fmaf(zv[l], Ar[l][j], a);
                zn[j] = a;
            }
#pragma unroll
            for (int j = 0; j < LL; ++j) zv[j] = zn[j];
        }
        float acc = base;
#pragma unroll
        for (int c = 0; c < CC; ++c) acc = fmaf(xb[t * CC + c], wxv[c], acc);
#pragma unroll
        for (int l = 0; l < LL; ++l) acc = fmaf(zv[l], wzv[l], acc);
        acc = fminf(fmaxf(acc, -CLIP), CLIP);
        float cmv = (v < NBERN) ? (1.0f / (1.0f + __expf(-acc))) : __expf(acc);
        lp[(size_t)t * VV] = acc;
        cm[(size_t)t * VV] = cmv;
    }
}

extern "C" void kernel_launch(void* const* d_in, const int* in_sizes, int n_in,
                              void* d_out, int out_size, void* d_ws, size_t ws_size,
                              hipStream_t stream) {
    const float* eps        = (const float*)d_in[0];
    const float* u          = (const float*)d_in[1];
    const float* x          = (const float*)d_in[2];
    const float* A          = (const float*)d_in[3];
    const float* logvar_z1  = (const float*)d_in[4];
    const float* beta0      = (const float*)d_in[5];
    const float* beta1      = (const float*)d_in[6];
    const float* intercepts = (const float*)d_in[7];
    const float* wz         = (const float*)d_in[8];
    const float* wx         = (const float*)d_in[9];
    const float* logvar_u   = (const float*)d_in[10];

    float* linpar   = (float*)d_out;
    float* condmean = (float*)d_out + (size_t)BB * TT * VV;

    const size_t z_bytes = (size_t)BB * TT * LL * sizeof(float);
    if (ws_size >= z_bytes) {
        float* zws = (float*)d_ws;
        hipLaunchKernelGGL(var1_fast, dim3(BB * LL / 256), dim3(256), 0, stream,
                           eps, A, logvar_z1, beta0, beta1, zws);
        hipLaunchKernelGGL(link_nt, dim3(LBLK), dim3(256), 0, stream,
                           zws, u, x, intercepts, wz, wx, logvar_u, linpar, condmean);
    } else {
        hipLaunchKernelGGL(vargllvm_fused, dim3(BB / 4), dim3(256), 0, stream,
                           eps, u, x, A, logvar_z1, beta0, beta1,
                           intercepts, wz, wx, logvar_u, linpar, condmean);
    }
}